// Round 14
// baseline (176.295 us; speedup 1.0000x reference)
//
#include <hip/hip_runtime.h>
#include <stdint.h>

// Match reference numerics: no FMA contraction anywhere (discrete IoU>thres
// decisions flip on 1-ulp differences).
#pragma clang fp contract(off)

#define BATCH 32
#define NPRED 25200
#define ROWF 9
#define TOPK 1000
#define SUBS 8
#define ROWS_PER_SUB (NPRED / SUBS)   // 3150
#define SUBCAP 512
#define CONF_T 0.7f
#define IOU_T 0.45f
#define KW 16          // 1000 bits -> 16 u64 words
#define SUPROW 1024    // global sup stride per word-column
#define TKROW 1024     // bx/sa stride per image

typedef unsigned long long u64;
typedef unsigned int u32;

// ---- workspace layout (bytes) ----
#define WS_CAND 0                      // 256 lists x 512 u64 = 1,048,576
#define WS_BX   (1048576)              // 32 x 1024 float4    =   524,288
#define WS_SA   (WS_BX + 524288)       // 32 x 1024 float4    =   524,288
#define WS_SUP  (WS_SA + 524288)       // 32 x 16 x 1024 u64  = 4,194,304
#define WS_FLAGS (WS_SUP + 4194304)    // 32 u32

// Session notes baked in:
//  - R8: grid-wide cooperative grid.sync ~60+ us/sync. Never.
//  - R11: SPIN-POLLING device-scope barriers stall ~145 us total. Never poll.
//  - R14: last-arriver detection (one fetch_add per block, 7/8 exit, no
//    polling) is the only acceptable inter-block sync; per-image pipelining.
//  - R9: LDS-broadcast loops concentrated on few CUs serialize on the per-CU
//    LDS pipe -> supmat broadcasts via v_readlane (VALU), 8 blocks/image.
//  - R12: top-1000 rows gathered ONCE (rank kernel), SoA after that.
//  - R13: intra-kernel shavings are exhausted; only dispatch count remains.

__device__ __forceinline__ u64 readlane64(u64 v, int l) {
    // wave-uniform lane index -> v_readlane_b32 x2 (VALU, no LDS pipe)
    u32 lo = __builtin_amdgcn_readlane((u32)v, (u32)l);
    u32 hi = __builtin_amdgcn_readlane((u32)(v >> 32), (u32)l);
    return ((u64)hi << 32) | lo;
}
__device__ __forceinline__ float readlanef(float v, int l) {
    return __uint_as_float(__builtin_amdgcn_readlane(__float_as_uint(v), (u32)l));
}
__device__ __forceinline__ u64 shflxor64(u64 v, int m) {
    u32 lo = __shfl_xor((u32)v, m, 64);
    u32 hi = __shfl_xor((u32)(v >> 32), m, 64);
    return ((u64)hi << 32) | lo;
}

// K1: compact valid rows of one (image, sub-range) into keys, then bitonic-sort
// 512 keys (descending; zeros pad the tail). key = (float_bits(conf)<<32) | ~row
// -> desc order == (score desc, idx asc), exactly jax.lax.top_k tie-breaking.
// ~317 valid rows per 3150 expected; SUBCAP=512 is mean+11.5 sigma.
// Hybrid bitonic: 39 in-wave passes via __shfl_xor, 6 cross-wave via LDS.
// Also zeroes bx/sa slices and the per-image flags (0xAA-poisoned ws).
__global__ __launch_bounds__(512) void compact_sort_kernel(const float* __restrict__ pred,
                                                           u64* __restrict__ cand_ws,
                                                           float4* __restrict__ bx_ws,
                                                           float4* __restrict__ sa_ws,
                                                           u32* __restrict__ flags) {
    __shared__ u64 skey[SUBCAP];          // 4096 B
    __shared__ u32 cnt;
    int bs = blockIdx.x;          // 0..255
    int b = bs >> 3, s = bs & 7;
    int tid = threadIdx.x;
    if (tid == 0) cnt = 0;
    skey[tid] = 0;
    if (tid < 128) {
        float4 z = make_float4(0.f, 0.f, 0.f, 0.f);
        bx_ws[(size_t)b * TKROW + s * 128 + tid] = z;
        sa_ws[(size_t)b * TKROW + s * 128 + tid] = z;
    }
    if (tid == 0 && bs < BATCH) flags[bs] = 0;   // visible to K3 via launch boundary
    __syncthreads();

    // gather cols 4,5 for my rows: r = r0 + tid + k*512, k=0..6 (3150 = 6*512+78)
    int r0 = s * ROWS_PER_SUB;
    const int NCH = (ROWS_PER_SUB + 511) / 512;   // 7
    float objv[NCH], clsv[NCH];
#pragma unroll
    for (int k = 0; k < NCH; ++k) {
        int r = tid + k * 512;
        if (r < ROWS_PER_SUB) {
            size_t base = ((size_t)b * NPRED + r0 + r) * ROWF;
            objv[k] = pred[base + 4];
            clsv[k] = pred[base + 5];
        }
    }
#pragma unroll
    for (int k = 0; k < NCH; ++k) {
        int r = tid + k * 512;
        if (r < ROWS_PER_SUB) {
            float conf = objv[k] * clsv[k];
            if (objv[k] > CONF_T && conf > CONF_T) {
                int row = r0 + r;
                u32 slot = atomicAdd(&cnt, 1u);
                if (slot < SUBCAP)
                    skey[slot] = ((u64)__float_as_uint(conf) << 32) | (u64)(u32)(~(u32)row);
            }
        }
    }
    __syncthreads();

    // hybrid bitonic sort, descending, 512 elements, one key/thread
    u64 key = skey[tid];
    bool wrote = true;   // skey currently matches registers
    for (int k = 2; k <= SUBCAP; k <<= 1) {
        for (int j = k >> 1; j > 0; j >>= 1) {
            bool desc = ((tid & k) == 0);
            bool up = ((tid & j) == 0);     // I'm the lower index of the pair
            u64 part;
            if (j >= 64) {
                if (!wrote) { __syncthreads(); skey[tid] = key; }
                __syncthreads();
                part = skey[tid ^ j];
                wrote = false;              // registers will diverge from skey
            } else {
                part = shflxor64(key, j);
                wrote = false;
            }
            bool takemax = (desc == up);    // desc: lower holds larger
            u64 mx = key > part ? key : part;
            u64 mn = key > part ? part : key;
            key = takemax ? mx : mn;
        }
    }
    cand_ws[(size_t)bs * SUBCAP + tid] = key;
}

// K2: rank + gather + publish SoA. 8 blocks per image; each block ranks its
// own sub-list's 512 keys (rank = sum over all 8 sorted lists of count(>key);
// keys unique -> ranks exact/unique). For rank < TOPK, gather the pred row
// ONCE, compute the box (identical FP expressions), and scatter
// bx_ws[b][rank] = (x1,y1,x2,y2), sa_ws[b][rank] = (score,p6,p7,p8).
__global__ __launch_bounds__(512) void rank_kernel(const float* __restrict__ pred,
                                                   const u64* __restrict__ cand_ws,
                                                   float4* __restrict__ bx_ws,
                                                   float4* __restrict__ sa_ws) {
    __shared__ u64 lists[SUBS * SUBCAP];   // 32 KB
    int bs = blockIdx.x;          // 0..255
    int b = bs >> 3, s = bs & 7;
    int tid = threadIdx.x;
    const u64* src = cand_ws + (size_t)b * SUBS * SUBCAP;
    for (int t = tid; t < SUBS * SUBCAP; t += 512) lists[t] = src[t];
    __syncthreads();
    u64 key = lists[(s << 9) + tid];
    if (key) {
        int lo[SUBS];
#pragma unroll
        for (int l = 0; l < SUBS; ++l) lo[l] = 0;
#pragma unroll
        for (int w2 = SUBCAP; w2 >= 1; w2 >>= 1) {   // 10 rounds
#pragma unroll
            for (int l = 0; l < SUBS; ++l) {
                int p = lo[l] + w2;
                if (p <= SUBCAP && lists[(l << 9) + p - 1] > key) lo[l] = p;
            }
        }
        int rank = 0;
#pragma unroll
        for (int l = 0; l < SUBS; ++l) rank += lo[l];
        if (rank < TOPK) {
            u32 r = ~(u32)key;
            const float* p = pred + ((size_t)b * NPRED + r) * ROWF;
            float x = p[0], y = p[1], wd = p[2], hh = p[3];
            float4 box = make_float4(x - wd * 0.5f, y - hh * 0.5f,
                                     x + wd * 0.5f, y + hh * 0.5f);
            float4 sa = make_float4(__uint_as_float((u32)(key >> 32)),
                                    p[6], p[7], p[8]);
            bx_ws[(size_t)b * TKROW + rank] = box;
            sa_ws[(size_t)b * TKROW + rank] = sa;
        }
    }
}

// K3 (fused supmat + last-arriver scan + output). 256 blocks (8/image).
// Supmat: 136 upper-tri 64x64 tiles/image, one per wave; j-tile rows in lane
// registers, per-j broadcast via v_readlane (VALU; R9 lesson). Then each
// block does threadfence + one ACQ_REL fetch_add on the image's flag; 7/8
// retire, the last block runs the sparse register greedy scan + output
// (R14: no polling -- the only cheap inter-block sync on this part).
__global__ __launch_bounds__(1024) void supscan_kernel(const float4* __restrict__ bx_ws,
                                                       const float4* __restrict__ sa_ws,
                                                       u64* __restrict__ sup_g,
                                                       u32* __restrict__ flags,
                                                       float* __restrict__ out,
                                                       float* __restrict__ keepout) {
    __shared__ float4 bx_s[1024];   // 16 KB
    __shared__ float  ar_s[1024];   // 4 KB
    __shared__ u64 keep_lds[KW];
    __shared__ u64 acc_lds;
    __shared__ u32 last_sh;
    int b = blockIdx.x >> 3, q = blockIdx.x & 7;
    int tid = threadIdx.x;
    int w = tid >> 6, lane = tid & 63;

    // ---- supmat phase ----
    {
        float4 box = bx_ws[(size_t)b * TKROW + tid];  // slots>=TOPK zeroed in K1
        bx_s[tid] = box;
        ar_s[tid] = (box.z - box.x) * (box.w - box.y); // zero box -> ar 0 -> iou 0
    }
    __syncthreads();
    for (int pass = 0; pass < 2; ++pass) {
        int t = (pass == 0) ? (q * 16 + w) : ((w == 15) ? 128 + q : 136);
        if (t >= 136) continue;
        // decode tile t -> (iw, jw), jw >= iw
        int iw = 0, rem = t, c = 16;
        while (rem >= c) { rem -= c; c--; iw++; }
        int jw = iw + rem;
        int i = iw * 64 + lane;
        bool act = i < TOPK;
        float4 bi4 = bx_s[i];
        float ai = ar_s[i];
        float4 bja = bx_s[(jw << 6) + lane];    // this lane's j-row
        float aja = ar_s[(jw << 6) + lane];
        u64 m = 0;
        int jbase = jw << 6;
        for (int l2 = 0; l2 < 64; ++l2) {
            float bjx = readlanef(bja.x, l2);
            float bjy = readlanef(bja.y, l2);
            float bjz = readlanef(bja.z, l2);
            float bjw = readlanef(bja.w, l2);
            float aj  = readlanef(aja, l2);
            float lx = fmaxf(bi4.x, bjx);
            float ly = fmaxf(bi4.y, bjy);
            float rx = fminf(bi4.z, bjz);
            float ry = fminf(bi4.w, bjw);
            float iw2 = rx - lx; iw2 = iw2 > 0.f ? iw2 : 0.f;
            float ih = ry - ly; ih = ih > 0.f ? ih : 0.f;
            float inter = iw2 * ih;
            float den = ai + aj - inter + 1e-7f;  // ((ai+aj)-inter)+eps, ref order
            float iou = inter / den;
            if (act && (jbase + l2) > i && iou > IOU_T) m |= 1ull << l2;
        }
        if (act) sup_g[((size_t)b * KW + jw) * SUPROW + i] = m;
    }

    // ---- last-arriver: 1 fence + 1 atomic per block, NO polling ----
    __threadfence();
    __syncthreads();
    if (tid == 0)
        last_sh = __hip_atomic_fetch_add(&flags[b], 1u, __ATOMIC_ACQ_REL,
                                         __HIP_MEMORY_SCOPE_AGENT);
    __syncthreads();
    if (last_sh != 7u) return;      // 7/8 blocks retire; last one scans

    // ---- scan phase (only the image's last-arriving block) ----
    const u64* S = sup_g + (size_t)b * KW * SUPROW;
    float4 sa = sa_ws[(size_t)b * TKROW + tid];   // slots >= TOPK are zero
    u64 keep0 = __ballot(sa.x != 0.f);            // row w*64+lane occupied
    if (lane == 0) keep_lds[w] = keep0;

    u64 sup_reg[KW];
    u64 diagreg = 0;
#pragma unroll
    for (int bi = 0; bi < KW; ++bi) {
        sup_reg[bi] = 0;
        if (bi <= w)    // wave-uniform; bi>w never used
            sup_reg[bi] = S[(size_t)w * SUPROW + (bi << 6) + lane];
        if (bi == w) diagreg = sup_reg[bi];
    }
    __syncthreads();

    u64 nzmask = __ballot(diagreg != 0);   // rows of this word with in-word suppression

#pragma unroll
    for (int bi = 0; bi < KW; ++bi) {
        if (w == bi) {
            // serial greedy within word bi; only suppressor rows enter the loop
            u64 cur = keep_lds[bi];
            u64 active = cur & nzmask;
            while (active) {
                int i = __ffsll((long long)active) - 1;
                u64 wi = readlane64(diagreg, i);   // row i's mask (bits > i only)
                active &= active - 1;              // retire bit i
                cur &= ~wi;
                active &= ~wi;                     // suppressed rows can't suppress
            }
            if (lane == 0) { keep_lds[bi] = cur; acc_lds = cur; }
        }
        __syncthreads();
        if (w > bi) {
            u64 A = acc_lds;                       // accepted set of block bi
            u64 myv = sup_reg[bi];                 // row (bi*64+lane)'s mask over word w
            bool accb = (A >> lane) & 1ull;
            u64 lanes = __ballot(accb && myv != 0ull);
            if (lanes) {                           // rare: sparse suppression
                u64 wred = 0;
                while (lanes) {
                    int l = __ffsll((long long)lanes) - 1;
                    wred |= readlane64(myv, l);
                    lanes &= lanes - 1;
                }
                if (lane == 0) keep_lds[w] &= ~wred;
            }
        }
        __syncthreads();
    }

    if (tid < TOPK) {
        bool kp = ((keep_lds[w] >> lane) & 1ull) != 0;
        float4 bx = bx_s[tid];                    // still resident in LDS
        size_t ob = ((size_t)b * TOPK + tid) * ROWF;
        out[ob + 0] = kp ? bx.x : 0.f;
        out[ob + 1] = kp ? bx.y : 0.f;
        out[ob + 2] = kp ? bx.z : 0.f;
        out[ob + 3] = kp ? bx.w : 0.f;
        out[ob + 4] = kp ? sa.x : 0.f;
        out[ob + 5] = 0.f;
        out[ob + 6] = kp ? sa.y : 0.f;
        out[ob + 7] = kp ? sa.z : 0.f;
        out[ob + 8] = kp ? sa.w : 0.f;
        keepout[(size_t)b * TOPK + tid] = kp ? 1.0f : 0.0f;
    }
}

extern "C" void kernel_launch(void* const* d_in, const int* in_sizes, int n_in,
                              void* d_out, int out_size, void* d_ws, size_t ws_size,
                              hipStream_t stream) {
    const float* pred = (const float*)d_in[0];
    float* out = (float*)d_out;                         // [32,1000,9]
    float* keepout = out + (size_t)BATCH * TOPK * ROWF; // [32,1000]
    char* ws = (char*)d_ws;
    u64* cand_ws = (u64*)(ws + WS_CAND);
    float4* bx_ws = (float4*)(ws + WS_BX);
    float4* sa_ws = (float4*)(ws + WS_SA);
    u64* sup_g = (u64*)(ws + WS_SUP);
    u32* flags = (u32*)(ws + WS_FLAGS);

    compact_sort_kernel<<<BATCH * SUBS, 512, 0, stream>>>(pred, cand_ws, bx_ws, sa_ws, flags);
    rank_kernel<<<BATCH * SUBS, 512, 0, stream>>>(pred, cand_ws, bx_ws, sa_ws);
    supscan_kernel<<<BATCH * SUBS, 1024, 0, stream>>>(bx_ws, sa_ws, sup_g, flags, out, keepout);
}

// Round 15
// 123.107 us; speedup vs baseline: 1.4320x; 1.4320x over previous
//
#include <hip/hip_runtime.h>
#include <stdint.h>

// Match reference numerics: no FMA contraction anywhere (discrete IoU>thres
// decisions flip on 1-ulp differences).
#pragma clang fp contract(off)

#define BATCH 32
#define NPRED 25200
#define ROWF 9
#define TOPK 1000
#define SUBS 8
#define ROWS_PER_SUB (NPRED / SUBS)   // 3150
#define SUBCAP 512
#define CONF_T 0.7f
#define IOU_T 0.45f
#define KW 16          // 1000 bits -> 16 u64 words
#define SUPROW 1024    // global sup stride per word-column
#define TKROW 1024     // bx/sa stride per image

typedef unsigned long long u64;
typedef unsigned int u32;

// ---- workspace layout (bytes) ----
#define WS_CAND 0                      // 256 lists x 512 u64 = 1,048,576
#define WS_BX   (1048576)              // 32 x 1024 float4    =   524,288
#define WS_SA   (WS_BX + 524288)       // 32 x 1024 float4    =   524,288
#define WS_SUP  (WS_SA + 524288)       // 32 x 16 x 1024 u64  = 4,194,304

// Session laws (all measured on this part):
//  - R8: grid-wide cooperative grid.sync ~60 us/sync. Never.
//  - R11: spin-polling device-scope barriers stall ~145 us. Never poll.
//  - R14: even a single per-block agent-scope fence+atomic costs ~0.34 us/block
//    (L2 writeback across XCDs) -> 256 blocks = +87 us. Device-scope sync
//    scales with block count; a ~6 us launch boundary ALWAYS wins.
//  - R9: LDS-broadcast loops concentrated on few CUs serialize on the per-CU
//    LDS pipe -> supmat at 8 blocks/image, broadcasts via v_readlane (VALU).
//  - R12: top-1000 rows gathered ONCE (rank kernel), SoA after that.
//  - R13: intra-kernel shavings beyond this are neutral; 4-dispatch split is
//    the structural floor.

__device__ __forceinline__ u64 readlane64(u64 v, int l) {
    // wave-uniform lane index -> v_readlane_b32 x2 (VALU, no LDS pipe)
    u32 lo = __builtin_amdgcn_readlane((u32)v, (u32)l);
    u32 hi = __builtin_amdgcn_readlane((u32)(v >> 32), (u32)l);
    return ((u64)hi << 32) | lo;
}
__device__ __forceinline__ float readlanef(float v, int l) {
    return __uint_as_float(__builtin_amdgcn_readlane(__float_as_uint(v), (u32)l));
}
__device__ __forceinline__ u64 shflxor64(u64 v, int m) {
    u32 lo = __shfl_xor((u32)v, m, 64);
    u32 hi = __shfl_xor((u32)(v >> 32), m, 64);
    return ((u64)hi << 32) | lo;
}

// K1: compact valid rows of one (image, sub-range) into keys, then bitonic-sort
// 512 keys (descending; zeros pad the tail). key = (float_bits(conf)<<32) | ~row
// -> desc order == (score desc, idx asc), exactly jax.lax.top_k tie-breaking.
// ~317 valid rows per 3150 expected; SUBCAP=512 is mean+11.5 sigma.
// Hybrid bitonic: 39 in-wave passes via __shfl_xor, 6 cross-wave via LDS.
// Also zeroes bx/sa slices (0xAA-poisoned ws; rank only writes rank<TOPK).
__global__ __launch_bounds__(512) void compact_sort_kernel(const float* __restrict__ pred,
                                                           u64* __restrict__ cand_ws,
                                                           float4* __restrict__ bx_ws,
                                                           float4* __restrict__ sa_ws) {
    __shared__ u64 skey[SUBCAP];          // 4096 B
    __shared__ u32 cnt;
    int bs = blockIdx.x;          // 0..255
    int b = bs >> 3, s = bs & 7;
    int tid = threadIdx.x;
    if (tid == 0) cnt = 0;
    skey[tid] = 0;
    if (tid < 128) {
        float4 z = make_float4(0.f, 0.f, 0.f, 0.f);
        bx_ws[(size_t)b * TKROW + s * 128 + tid] = z;
        sa_ws[(size_t)b * TKROW + s * 128 + tid] = z;
    }
    __syncthreads();

    // gather cols 4,5 for my rows: r = r0 + tid + k*512, k=0..6 (3150 = 6*512+78)
    int r0 = s * ROWS_PER_SUB;
    const int NCH = (ROWS_PER_SUB + 511) / 512;   // 7
    float objv[NCH], clsv[NCH];
#pragma unroll
    for (int k = 0; k < NCH; ++k) {
        int r = tid + k * 512;
        if (r < ROWS_PER_SUB) {
            size_t base = ((size_t)b * NPRED + r0 + r) * ROWF;
            objv[k] = pred[base + 4];
            clsv[k] = pred[base + 5];
        }
    }
#pragma unroll
    for (int k = 0; k < NCH; ++k) {
        int r = tid + k * 512;
        if (r < ROWS_PER_SUB) {
            float conf = objv[k] * clsv[k];
            if (objv[k] > CONF_T && conf > CONF_T) {
                int row = r0 + r;
                u32 slot = atomicAdd(&cnt, 1u);
                if (slot < SUBCAP)
                    skey[slot] = ((u64)__float_as_uint(conf) << 32) | (u64)(u32)(~(u32)row);
            }
        }
    }
    __syncthreads();

    // hybrid bitonic sort, descending, 512 elements, one key/thread
    u64 key = skey[tid];
    bool wrote = true;   // skey currently matches registers
    for (int k = 2; k <= SUBCAP; k <<= 1) {
        for (int j = k >> 1; j > 0; j >>= 1) {
            bool desc = ((tid & k) == 0);
            bool up = ((tid & j) == 0);     // I'm the lower index of the pair
            u64 part;
            if (j >= 64) {
                if (!wrote) { __syncthreads(); skey[tid] = key; }
                __syncthreads();
                part = skey[tid ^ j];
                wrote = false;              // registers will diverge from skey
            } else {
                part = shflxor64(key, j);
                wrote = false;
            }
            bool takemax = (desc == up);    // desc: lower holds larger
            u64 mx = key > part ? key : part;
            u64 mn = key > part ? part : key;
            key = takemax ? mx : mn;
        }
    }
    cand_ws[(size_t)bs * SUBCAP + tid] = key;
}

// K2: rank + gather + publish SoA. 8 blocks per image; each block ranks its
// own sub-list's 512 keys (rank = sum over all 8 sorted lists of count(>key);
// keys unique -> ranks exact/unique). For rank < TOPK, gather the pred row
// ONCE, compute the box (identical FP expressions), and scatter
// bx_ws[b][rank] = (x1,y1,x2,y2), sa_ws[b][rank] = (score,p6,p7,p8).
__global__ __launch_bounds__(512) void rank_kernel(const float* __restrict__ pred,
                                                   const u64* __restrict__ cand_ws,
                                                   float4* __restrict__ bx_ws,
                                                   float4* __restrict__ sa_ws) {
    __shared__ u64 lists[SUBS * SUBCAP];   // 32 KB
    int bs = blockIdx.x;          // 0..255
    int b = bs >> 3, s = bs & 7;
    int tid = threadIdx.x;
    const u64* src = cand_ws + (size_t)b * SUBS * SUBCAP;
    for (int t = tid; t < SUBS * SUBCAP; t += 512) lists[t] = src[t];
    __syncthreads();
    u64 key = lists[(s << 9) + tid];
    if (key) {
        int lo[SUBS];
#pragma unroll
        for (int l = 0; l < SUBS; ++l) lo[l] = 0;
#pragma unroll
        for (int w2 = SUBCAP; w2 >= 1; w2 >>= 1) {   // 10 rounds
#pragma unroll
            for (int l = 0; l < SUBS; ++l) {
                int p = lo[l] + w2;
                if (p <= SUBCAP && lists[(l << 9) + p - 1] > key) lo[l] = p;
            }
        }
        int rank = 0;
#pragma unroll
        for (int l = 0; l < SUBS; ++l) rank += lo[l];
        if (rank < TOPK) {
            u32 r = ~(u32)key;
            const float* p = pred + ((size_t)b * NPRED + r) * ROWF;
            float x = p[0], y = p[1], wd = p[2], hh = p[3];
            float4 box = make_float4(x - wd * 0.5f, y - hh * 0.5f,
                                     x + wd * 0.5f, y + hh * 0.5f);
            float4 sa = make_float4(__uint_as_float((u32)(key >> 32)),
                                    p[6], p[7], p[8]);
            bx_ws[(size_t)b * TKROW + rank] = box;
            sa_ws[(size_t)b * TKROW + rank] = sa;
        }
    }
}

// K3: suppression matrix as 136 upper-triangle 64x64 tiles per image,
// one tile per wave (8 blocks/image x 16 waves). j-tile rows live in lane
// registers; per-j broadcast via v_readlane (VALU) -- 2 LDS reads per tile
// instead of 128 (R9 lesson: per-CU LDS pipe is the scarce resource).
__global__ __launch_bounds__(1024) void supmat_kernel(const float4* __restrict__ bx_ws,
                                                      u64* __restrict__ sup_g) {
    __shared__ float4 bx_s[1024];   // 16 KB
    __shared__ float  ar_s[1024];   // 4 KB
    int b = blockIdx.x >> 3, q = blockIdx.x & 7;
    int tid = threadIdx.x;
    {
        float4 box = bx_ws[(size_t)b * TKROW + tid];  // slots>=TOPK zeroed in K1
        bx_s[tid] = box;
        ar_s[tid] = (box.z - box.x) * (box.w - box.y); // zero box -> ar 0 -> iou 0
    }
    __syncthreads();
    int wave = tid >> 6, lane = tid & 63;
    for (int pass = 0; pass < 2; ++pass) {
        int t = (pass == 0) ? (q * 16 + wave) : ((wave == 15) ? 128 + q : 136);
        if (t >= 136) continue;
        // decode tile t -> (iw, jw), jw >= iw
        int iw = 0, rem = t, c = 16;
        while (rem >= c) { rem -= c; c--; iw++; }
        int jw = iw + rem;
        int i = iw * 64 + lane;
        bool act = i < TOPK;
        float4 bi4 = bx_s[i];
        float ai = ar_s[i];
        float4 bja = bx_s[(jw << 6) + lane];    // this lane's j-row
        float aja = ar_s[(jw << 6) + lane];
        u64 m = 0;
        int jbase = jw << 6;
        for (int l2 = 0; l2 < 64; ++l2) {
            float bjx = readlanef(bja.x, l2);
            float bjy = readlanef(bja.y, l2);
            float bjz = readlanef(bja.z, l2);
            float bjw = readlanef(bja.w, l2);
            float aj  = readlanef(aja, l2);
            float lx = fmaxf(bi4.x, bjx);
            float ly = fmaxf(bi4.y, bjy);
            float rx = fminf(bi4.z, bjz);
            float ry = fminf(bi4.w, bjw);
            float iw2 = rx - lx; iw2 = iw2 > 0.f ? iw2 : 0.f;
            float ih = ry - ly; ih = ih > 0.f ? ih : 0.f;
            float inter = iw2 * ih;
            float den = ai + aj - inter + 1e-7f;  // ((ai+aj)-inter)+eps, ref order
            float iou = inter / den;
            if (act && (jbase + l2) > i && iou > IOU_T) m |= 1ull << l2;
        }
        if (act) sup_g[((size_t)b * KW + jw) * SUPROW + i] = m;
    }
}

// K4: sparse register-resident greedy scan + output, all inputs coalesced SoA.
// keep0 from score!=0 via ballot. Serial loop only visits rows that actually
// suppress (ballot-gated); uniform broadcasts via v_readlane (VALU pipe).
// Preload gated to bi<=w (wave-uniform) -- halves the sup_g traffic.
__global__ __launch_bounds__(1024) void scan_out_kernel(const float4* __restrict__ bx_ws,
                                                        const float4* __restrict__ sa_ws,
                                                        const u64* __restrict__ sup_g,
                                                        float* __restrict__ out,
                                                        float* __restrict__ keepout) {
    __shared__ u64 keep_lds[KW];
    __shared__ u64 acc_lds;
    int b = blockIdx.x, tid = threadIdx.x;
    int w = tid >> 6, lane = tid & 63;
    const u64* S = sup_g + (size_t)b * KW * SUPROW;

    float4 sa = sa_ws[(size_t)b * TKROW + tid];   // slots >= TOPK are zero
    u64 keep0 = __ballot(sa.x != 0.f);            // row w*64+lane occupied
    if (lane == 0) keep_lds[w] = keep0;

    u64 sup_reg[KW];
    u64 diagreg = 0;
#pragma unroll
    for (int bi = 0; bi < KW; ++bi) {
        sup_reg[bi] = 0;
        if (bi <= w)    // wave-uniform; bi>w never used
            sup_reg[bi] = S[(size_t)w * SUPROW + (bi << 6) + lane];
        if (bi == w) diagreg = sup_reg[bi];
    }
    __syncthreads();

    u64 nzmask = __ballot(diagreg != 0);   // rows of this word with in-word suppression

#pragma unroll
    for (int bi = 0; bi < KW; ++bi) {
        if (w == bi) {
            // serial greedy within word bi; only suppressor rows enter the loop
            u64 cur = keep_lds[bi];
            u64 active = cur & nzmask;
            while (active) {
                int i = __ffsll((long long)active) - 1;
                u64 wi = readlane64(diagreg, i);   // row i's mask (bits > i only)
                active &= active - 1;              // retire bit i
                cur &= ~wi;
                active &= ~wi;                     // suppressed rows can't suppress
            }
            if (lane == 0) { keep_lds[bi] = cur; acc_lds = cur; }
        }
        __syncthreads();
        if (w > bi) {
            u64 A = acc_lds;                       // accepted set of block bi
            u64 myv = sup_reg[bi];                 // row (bi*64+lane)'s mask over word w
            bool accb = (A >> lane) & 1ull;
            u64 lanes = __ballot(accb && myv != 0ull);
            if (lanes) {                           // rare: sparse suppression
                u64 wred = 0;
                while (lanes) {
                    int l = __ffsll((long long)lanes) - 1;
                    wred |= readlane64(myv, l);
                    lanes &= lanes - 1;
                }
                if (lane == 0) keep_lds[w] &= ~wred;
            }
        }
        __syncthreads();
    }

    if (tid < TOPK) {
        bool kp = ((keep_lds[w] >> lane) & 1ull) != 0;
        float4 bx = bx_ws[(size_t)b * TKROW + tid];  // coalesced
        size_t ob = ((size_t)b * TOPK + tid) * ROWF;
        out[ob + 0] = kp ? bx.x : 0.f;
        out[ob + 1] = kp ? bx.y : 0.f;
        out[ob + 2] = kp ? bx.z : 0.f;
        out[ob + 3] = kp ? bx.w : 0.f;
        out[ob + 4] = kp ? sa.x : 0.f;
        out[ob + 5] = 0.f;
        out[ob + 6] = kp ? sa.y : 0.f;
        out[ob + 7] = kp ? sa.z : 0.f;
        out[ob + 8] = kp ? sa.w : 0.f;
        keepout[(size_t)b * TOPK + tid] = kp ? 1.0f : 0.0f;
    }
}

extern "C" void kernel_launch(void* const* d_in, const int* in_sizes, int n_in,
                              void* d_out, int out_size, void* d_ws, size_t ws_size,
                              hipStream_t stream) {
    const float* pred = (const float*)d_in[0];
    float* out = (float*)d_out;                         // [32,1000,9]
    float* keepout = out + (size_t)BATCH * TOPK * ROWF; // [32,1000]
    char* ws = (char*)d_ws;
    u64* cand_ws = (u64*)(ws + WS_CAND);
    float4* bx_ws = (float4*)(ws + WS_BX);
    float4* sa_ws = (float4*)(ws + WS_SA);
    u64* sup_g = (u64*)(ws + WS_SUP);

    compact_sort_kernel<<<BATCH * SUBS, 512, 0, stream>>>(pred, cand_ws, bx_ws, sa_ws);
    rank_kernel<<<BATCH * SUBS, 512, 0, stream>>>(pred, cand_ws, bx_ws, sa_ws);
    supmat_kernel<<<BATCH * SUBS, 1024, 0, stream>>>(bx_ws, sup_g);
    scan_out_kernel<<<BATCH, 1024, 0, stream>>>(bx_ws, sa_ws, sup_g, out, keepout);
}